// Round 1
// baseline (306.815 us; speedup 1.0000x reference)
//
#include <hip/hip_runtime.h>

#define DM   2048
#define SEQ  2048
#define NB   2
#define NH   16
#define HD   128

typedef __bf16 bf16x8 __attribute__((ext_vector_type(8)));
typedef float f32x4 __attribute__((ext_vector_type(4)));
typedef unsigned short u16x4 __attribute__((ext_vector_type(4)));
typedef unsigned short u16x8 __attribute__((ext_vector_type(8)));

__device__ __forceinline__ unsigned short f2b(float f) {
  return __builtin_bit_cast(unsigned short, (__bf16)f);
}

__device__ __forceinline__ void gl_lds16(const void* g, void* l) {
  __builtin_amdgcn_global_load_lds(
      (const __attribute__((address_space(1))) void*)g,
      (__attribute__((address_space(3))) void*)l, 16, 0, 0);
}

// ---------------- kernel 1: x fp32 -> bf16 ----------------
__global__ void k_cvt_x(const float* __restrict__ x, unsigned short* __restrict__ xb) {
  int i = blockIdx.x * 256 + threadIdx.x;
  const float4* src = (const float4*)x + (size_t)i * 2;
  float4 a = src[0], c = src[1];
  u16x8 o;
  o[0] = f2b(a.x); o[1] = f2b(a.y); o[2] = f2b(a.z); o[3] = f2b(a.w);
  o[4] = f2b(c.x); o[5] = f2b(c.y); o[6] = f2b(c.z); o[7] = f2b(c.w);
  *((u16x8*)xb + i) = o;
}

// ---------------- kernel 2: W fp32 [K][N] -> bf16 Wt [N][K] ----------------
__global__ void k_cvt_w(const float* __restrict__ Wq, const float* __restrict__ Wk,
                        const float* __restrict__ Wv, unsigned short* __restrict__ wts) {
  const float* W = blockIdx.z == 0 ? Wq : (blockIdx.z == 1 ? Wk : Wv);
  unsigned short* out = wts + (size_t)blockIdx.z * DM * DM;
  __shared__ unsigned short t[64 * 68];  // t[col][row]
  int c0 = blockIdx.x * 64, r0 = blockIdx.y * 64;
  int tr = threadIdx.x >> 4, tc = (threadIdx.x & 15) * 4;
#pragma unroll
  for (int p = 0; p < 4; ++p) {
    int r = p * 16 + tr;
    float4 v = *(const float4*)(W + (size_t)(r0 + r) * DM + c0 + tc);
    t[(tc + 0) * 68 + r] = f2b(v.x);
    t[(tc + 1) * 68 + r] = f2b(v.y);
    t[(tc + 2) * 68 + r] = f2b(v.z);
    t[(tc + 3) * 68 + r] = f2b(v.w);
  }
  __syncthreads();
#pragma unroll
  for (int p = 0; p < 4; ++p) {
    int c = p * 16 + tr;
    u16x4 o = *(const u16x4*)&t[c * 68 + tc];
    *(u16x4*)(out + (size_t)(c0 + c) * DM + r0 + tc) = o;
  }
}

// ---------------- kernel 3: QKV GEMM (bf16 MFMA, m97-style) ----------------
// C = x[4096,2048] @ W[2048,2048] ; A row-major, B as Wt[n][k] (B^T row-major).
// z=0 -> Q [bh][s][d], z=1 -> K [bh][s][d], z=2 -> V transposed [bh][d][s].
__global__ __launch_bounds__(256) void k_qkv(
    const unsigned short* __restrict__ xb, const unsigned short* __restrict__ wts,
    unsigned short* __restrict__ qb, unsigned short* __restrict__ kb,
    unsigned short* __restrict__ vtb) {
  __shared__ unsigned short smem[128 * 136];  // A:[0,8192) B:[8192,16384); V-epilogue uses all
  const int z = blockIdx.z;
  const unsigned short* wt = wts + (size_t)z * DM * DM;
  const int m0 = blockIdx.x * 128;
  const int n0 = blockIdx.y * 128;
  const int tid = threadIdx.x;
  const int wave = tid >> 6, lane = tid & 63;
  const int lr = lane & 15, lg = lane >> 4;
  const int wr = wave >> 1, wc = wave & 1;

  f32x4 acc[4][4] = {};

  for (int kt = 0; kt < DM / 64; ++kt) {
#pragma unroll
    for (int p = 0; p < 4; ++p) {
      int e = (p * 256 + tid) * 8;
      int row = e >> 6;
      int sc = ((e >> 3) & 7) ^ (row & 7);
      gl_lds16(xb + (size_t)(m0 + row) * DM + kt * 64 + sc * 8, &smem[p * 2048 + wave * 512]);
      gl_lds16(wt + (size_t)(n0 + row) * DM + kt * 64 + sc * 8, &smem[8192 + p * 2048 + wave * 512]);
    }
    __syncthreads();
#pragma unroll
    for (int ks = 0; ks < 2; ++ks) {
      bf16x8 af[4], bfr[4];
#pragma unroll
      for (int mf = 0; mf < 4; ++mf) {
        int row = wr * 64 + mf * 16 + lr;
        af[mf] = *(const bf16x8*)&smem[row * 64 + ((lg + ks * 4) ^ (row & 7)) * 8];
      }
#pragma unroll
      for (int nf = 0; nf < 4; ++nf) {
        int row = wc * 64 + nf * 16 + lr;
        bfr[nf] = *(const bf16x8*)&smem[8192 + row * 64 + ((lg + ks * 4) ^ (row & 7)) * 8];
      }
#pragma unroll
      for (int mf = 0; mf < 4; ++mf)
#pragma unroll
        for (int nf = 0; nf < 4; ++nf)
          acc[mf][nf] = __builtin_amdgcn_mfma_f32_16x16x32_bf16(af[mf], bfr[nf], acc[mf][nf], 0, 0, 0);
    }
    __syncthreads();
  }

  if (z < 2) {
    unsigned short* out = z == 0 ? qb : kb;
#pragma unroll
    for (int mf = 0; mf < 4; ++mf)
#pragma unroll
      for (int nf = 0; nf < 4; ++nf) {
        int n = n0 + wc * 64 + nf * 16 + lr;
        int h = n >> 7, d = n & 127;
#pragma unroll
        for (int r = 0; r < 4; ++r) {
          int m = m0 + wr * 64 + mf * 16 + lg * 4 + r;
          int b = m >> 11, s = m & 2047;
          out[(((size_t)(b * NH + h)) * SEQ + s) * HD + d] = f2b(acc[mf][nf][r]);
        }
      }
  } else {
    // transpose C tile through LDS, write V^T [bh][d][s]
#pragma unroll
    for (int mf = 0; mf < 4; ++mf)
#pragma unroll
      for (int nf = 0; nf < 4; ++nf) {
        int dl = wc * 64 + nf * 16 + lr;
        int sl = wr * 64 + mf * 16 + lg * 4;
        u16x4 pk = {f2b(acc[mf][nf][0]), f2b(acc[mf][nf][1]),
                    f2b(acc[mf][nf][2]), f2b(acc[mf][nf][3])};
        *(u16x4*)&smem[dl * 136 + sl] = pk;
      }
    __syncthreads();
    int b = m0 >> 11, sbase = m0 & 2047;
#pragma unroll
    for (int p = 0; p < 8; ++p) {
      int dl = p * 16 + (tid >> 4);
      int c8 = (tid & 15) * 8;
      u16x8 v = *(const u16x8*)&smem[dl * 136 + c8];
      int n = n0 + dl;
      int h = n >> 7, d = n & 127;
      *(u16x8*)(vtb + (((size_t)(b * NH + h)) * HD + d) * SEQ + sbase + c8) = v;
    }
  }
}

// ---------------- kernel 4: causal flash attention ----------------
// grid (16 q-tiles, 32 bh). 4 waves x 32 q-rows. KV tiles of 64.
// S^T = K · Q^T (swapped -> softmax nearly lane-local), P via per-wave LDS, O = P·V.
__global__ __launch_bounds__(256) void k_attn(
    const unsigned short* __restrict__ qb, const unsigned short* __restrict__ kb,
    const unsigned short* __restrict__ vtb, float* __restrict__ out) {
  __shared__ unsigned short Kl[64 * 128];   // [kv][d], swizzled
  __shared__ unsigned short Vl[128 * 64];   // [d][kv], swizzled
  __shared__ unsigned short Pl[4][32 * 72]; // per-wave [q][kv], pad 72

  const int qt = 15 - blockIdx.x;  // heavy blocks first
  const int bh = blockIdx.y;
  const int b = bh >> 4, h = bh & 15;
  const int q0 = qt * 128;
  const int tid = threadIdx.x;
  const int wave = tid >> 6, lane = tid & 63;
  const int lr = lane & 15, lg = lane >> 4;

  const unsigned short* Qg = qb + (size_t)bh * SEQ * HD;
  const unsigned short* Kg = kb + (size_t)bh * SEQ * HD;
  const unsigned short* Vg = vtb + (size_t)bh * HD * SEQ;

  bf16x8 qf[2][4];
#pragma unroll
  for (int nf = 0; nf < 2; ++nf)
#pragma unroll
    for (int ks = 0; ks < 4; ++ks)
      qf[nf][ks] = *(const bf16x8*)&Qg[(size_t)(q0 + wave * 32 + nf * 16 + lr) * HD + ks * 32 + lg * 8];

  f32x4 oacc[2][8] = {};
  float mraw[2] = {-1e30f, -1e30f};
  float lsum[2] = {0.f, 0.f};
  const float C = 0.12751744155229827f;  // (1/sqrt(128)) * log2(e)

  const int ntiles = 2 * qt + 2;
  for (int t = 0; t < ntiles; ++t) {
    const int kv0 = t * 64;
#pragma unroll
    for (int p = 0; p < 4; ++p) {
      int e = (p * 256 + tid) * 8;
      {
        int row = e >> 7;
        int sc = ((e >> 3) & 15) ^ (row & 7);
        gl_lds16(Kg + (size_t)(kv0 + row) * HD + sc * 8, &Kl[p * 2048 + wave * 512]);
      }
      {
        int row = e >> 6;
        int sc = ((e >> 3) & 7) ^ (row & 7);
        gl_lds16(Vg + (size_t)row * SEQ + kv0 + sc * 8, &Vl[p * 2048 + wave * 512]);
      }
    }
    __syncthreads();

    f32x4 sacc[4][2] = {};
#pragma unroll
    for (int ks = 0; ks < 4; ++ks) {
      bf16x8 kf[4];
#pragma unroll
      for (int mf = 0; mf < 4; ++mf) {
        int row = mf * 16 + lr;
        kf[mf] = *(const bf16x8*)&Kl[row * 128 + ((lg + ks * 4) ^ (row & 7)) * 8];
      }
#pragma unroll
      for (int mf = 0; mf < 4; ++mf)
#pragma unroll
        for (int nf = 0; nf < 2; ++nf)
          sacc[mf][nf] = __builtin_amdgcn_mfma_f32_16x16x32_bf16(kf[mf], qf[nf][ks], sacc[mf][nf], 0, 0, 0);
    }

    if (t >= 2 * qt) {  // diagonal tiles: causal mask
#pragma unroll
      for (int mf = 0; mf < 4; ++mf)
#pragma unroll
        for (int nf = 0; nf < 2; ++nf)
#pragma unroll
          for (int r = 0; r < 4; ++r) {
            int kv = kv0 + mf * 16 + lg * 4 + r;
            int q = q0 + wave * 32 + nf * 16 + lr;
            if (kv > q) sacc[mf][nf][r] = -1e30f;
          }
    }

    float pfac[2];
#pragma unroll
    for (int nf = 0; nf < 2; ++nf) {
      float vm = -1e30f;
#pragma unroll
      for (int mf = 0; mf < 4; ++mf) {
        vm = fmaxf(vm, fmaxf(fmaxf(sacc[mf][nf][0], sacc[mf][nf][1]),
                             fmaxf(sacc[mf][nf][2], sacc[mf][nf][3])));
      }
      vm = fmaxf(vm, __shfl_xor(vm, 16));
      vm = fmaxf(vm, __shfl_xor(vm, 32));
      float nm = fmaxf(mraw[nf], vm);
      pfac[nf] = exp2f((mraw[nf] - nm) * C);
      float mC = nm * C;
      float ssum = 0.f;
#pragma unroll
      for (int mf = 0; mf < 4; ++mf)
#pragma unroll
        for (int r = 0; r < 4; ++r) {
          float pv = exp2f(sacc[mf][nf][r] * C - mC);
          sacc[mf][nf][r] = pv;
          ssum += pv;
        }
      ssum += __shfl_xor(ssum, 16);
      ssum += __shfl_xor(ssum, 32);
      lsum[nf] = lsum[nf] * pfac[nf] + ssum;
      mraw[nf] = nm;
    }

    // rescale O by per-row factor (redistribute col-stats -> row-stats)
#pragma unroll
    for (int mfp = 0; mfp < 2; ++mfp)
#pragma unroll
      for (int r = 0; r < 4; ++r) {
        float f = __shfl(pfac[mfp], lg * 4 + r);
#pragma unroll
        for (int nf8 = 0; nf8 < 8; ++nf8) oacc[mfp][nf8][r] *= f;
      }

    // P (bf16) -> per-wave LDS [q][kv]
#pragma unroll
    for (int mf = 0; mf < 4; ++mf)
#pragma unroll
      for (int nf = 0; nf < 2; ++nf) {
        u16x4 pk = {f2b(sacc[mf][nf][0]), f2b(sacc[mf][nf][1]),
                    f2b(sacc[mf][nf][2]), f2b(sacc[mf][nf][3])};
        *(u16x4*)&Pl[wave][(nf * 16 + lr) * 72 + mf * 16 + lg * 4] = pk;
      }
    asm volatile("s_waitcnt lgkmcnt(0)" ::: "memory");

    // O += P · V
#pragma unroll
    for (int ks2 = 0; ks2 < 2; ++ks2) {
      bf16x8 pf[2];
#pragma unroll
      for (int mfp = 0; mfp < 2; ++mfp)
        pf[mfp] = *(const bf16x8*)&Pl[wave][(mfp * 16 + lr) * 72 + ks2 * 32 + lg * 8];
#pragma unroll
      for (int nf8 = 0; nf8 < 8; ++nf8) {
        int row = nf8 * 16 + lr;
        bf16x8 vf = *(const bf16x8*)&Vl[row * 64 + ((lg + ks2 * 4) ^ (row & 7)) * 8];
#pragma unroll
        for (int mfp = 0; mfp < 2; ++mfp)
          oacc[mfp][nf8] = __builtin_amdgcn_mfma_f32_16x16x32_bf16(pf[mfp], vf, oacc[mfp][nf8], 0, 0, 0);
      }
    }
    __syncthreads();
  }

  // normalize + store fp32
#pragma unroll
  for (int mfp = 0; mfp < 2; ++mfp)
#pragma unroll
    for (int r = 0; r < 4; ++r) {
      float li = 1.0f / __shfl(lsum[mfp], lg * 4 + r);
      int q = q0 + wave * 32 + mfp * 16 + lg * 4 + r;
      float* orow = out + ((size_t)b * SEQ + q) * DM + h * HD;
#pragma unroll
      for (int nf8 = 0; nf8 < 8; ++nf8)
        orow[nf8 * 16 + lr] = oacc[mfp][nf8][r] * li;
    }
}

// ---------------- launcher ----------------
extern "C" void kernel_launch(void* const* d_in, const int* in_sizes, int n_in,
                              void* d_out, int out_size, void* d_ws, size_t ws_size,
                              hipStream_t stream) {
  const float* x  = (const float*)d_in[0];
  const float* Wq = (const float*)d_in[1];
  const float* Wk = (const float*)d_in[2];
  const float* Wv = (const float*)d_in[3];
  float* out = (float*)d_out;
  char* ws = (char*)d_ws;

  unsigned short* xb  = (unsigned short*)(ws);              // 4096x2048 bf16   (16 MB)
  unsigned short* wt  = (unsigned short*)(ws + 16777216);   // 3x 2048x2048 bf16 (24 MB)
  unsigned short* qb  = (unsigned short*)(ws + 41943040);   // [32][2048][128]  (16 MB)
  unsigned short* kb  = (unsigned short*)(ws + 58720256);   // [32][2048][128]  (16 MB)
  unsigned short* vtb = (unsigned short*)(ws + 75497472);   // [32][128][2048]  (16 MB)

  k_cvt_x<<<4096, 256, 0, stream>>>(x, xb);
  dim3 gw(32, 32, 3);
  k_cvt_w<<<gw, 256, 0, stream>>>(Wq, Wk, Wv, wt);
  dim3 gg(32, 16, 3);
  k_qkv<<<gg, 256, 0, stream>>>(xb, wt, qb, kb, vtb);
  dim3 ga(16, 32);
  k_attn<<<ga, 256, 0, stream>>>(qb, kb, vtb, out);
}

// Round 2
// 251.355 us; speedup vs baseline: 1.2206x; 1.2206x over previous
//
#include <hip/hip_runtime.h>

#define DM   2048
#define SEQ  2048
#define NB   2
#define NH   16
#define HD   128

typedef __bf16 bf16x8 __attribute__((ext_vector_type(8)));
typedef float f32x4 __attribute__((ext_vector_type(4)));
typedef unsigned short u16x4 __attribute__((ext_vector_type(4)));
typedef unsigned short u16x8 __attribute__((ext_vector_type(8)));

__device__ __forceinline__ unsigned short f2b(float f) {
  return __builtin_bit_cast(unsigned short, (__bf16)f);
}

__device__ __forceinline__ void gl_lds16(const void* g, void* l) {
  __builtin_amdgcn_global_load_lds(
      (const __attribute__((address_space(1))) void*)g,
      (__attribute__((address_space(3))) void*)l, 16, 0, 0);
}

// ---------------- kernel 1: x fp32 -> bf16 ----------------
__global__ void k_cvt_x(const float* __restrict__ x, unsigned short* __restrict__ xb) {
  int i = blockIdx.x * 256 + threadIdx.x;
  const float4* src = (const float4*)x + (size_t)i * 2;
  float4 a = src[0], c = src[1];
  u16x8 o;
  o[0] = f2b(a.x); o[1] = f2b(a.y); o[2] = f2b(a.z); o[3] = f2b(a.w);
  o[4] = f2b(c.x); o[5] = f2b(c.y); o[6] = f2b(c.z); o[7] = f2b(c.w);
  *((u16x8*)xb + i) = o;
}

// ---------------- kernel 2: W fp32 [K][N] -> bf16 Wt [N][K] ----------------
__global__ void k_cvt_w(const float* __restrict__ Wq, const float* __restrict__ Wk,
                        const float* __restrict__ Wv, unsigned short* __restrict__ wts) {
  const float* W = blockIdx.z == 0 ? Wq : (blockIdx.z == 1 ? Wk : Wv);
  unsigned short* out = wts + (size_t)blockIdx.z * DM * DM;
  __shared__ unsigned short t[64 * 68];  // t[col][row]
  int c0 = blockIdx.x * 64, r0 = blockIdx.y * 64;
  int tr = threadIdx.x >> 4, tc = (threadIdx.x & 15) * 4;
#pragma unroll
  for (int p = 0; p < 4; ++p) {
    int r = p * 16 + tr;
    float4 v = *(const float4*)(W + (size_t)(r0 + r) * DM + c0 + tc);
    t[(tc + 0) * 68 + r] = f2b(v.x);
    t[(tc + 1) * 68 + r] = f2b(v.y);
    t[(tc + 2) * 68 + r] = f2b(v.z);
    t[(tc + 3) * 68 + r] = f2b(v.w);
  }
  __syncthreads();
#pragma unroll
  for (int p = 0; p < 4; ++p) {
    int c = p * 16 + tr;
    u16x4 o = *(const u16x4*)&t[c * 68 + tc];
    *(u16x4*)(out + (size_t)(c0 + c) * DM + r0 + tc) = o;
  }
}

// ---------------- kernel 3: QKV GEMM (bf16 MFMA, m97-style) ----------------
__global__ __launch_bounds__(256) void k_qkv(
    const unsigned short* __restrict__ xb, const unsigned short* __restrict__ wts,
    unsigned short* __restrict__ qb, unsigned short* __restrict__ kb,
    unsigned short* __restrict__ vtb) {
  __shared__ unsigned short smem[128 * 136];
  const int z = blockIdx.z;
  const unsigned short* wt = wts + (size_t)z * DM * DM;
  const int m0 = blockIdx.x * 128;
  const int n0 = blockIdx.y * 128;
  const int tid = threadIdx.x;
  const int wave = tid >> 6, lane = tid & 63;
  const int lr = lane & 15, lg = lane >> 4;
  const int wr = wave >> 1, wc = wave & 1;

  f32x4 acc[4][4] = {};

  for (int kt = 0; kt < DM / 64; ++kt) {
#pragma unroll
    for (int p = 0; p < 4; ++p) {
      int e = (p * 256 + tid) * 8;
      int row = e >> 6;
      int sc = ((e >> 3) & 7) ^ (row & 7);
      gl_lds16(xb + (size_t)(m0 + row) * DM + kt * 64 + sc * 8, &smem[p * 2048 + wave * 512]);
      gl_lds16(wt + (size_t)(n0 + row) * DM + kt * 64 + sc * 8, &smem[8192 + p * 2048 + wave * 512]);
    }
    __syncthreads();
#pragma unroll
    for (int ks = 0; ks < 2; ++ks) {
      bf16x8 af[4], bfr[4];
#pragma unroll
      for (int mf = 0; mf < 4; ++mf) {
        int row = wr * 64 + mf * 16 + lr;
        af[mf] = *(const bf16x8*)&smem[row * 64 + ((lg + ks * 4) ^ (row & 7)) * 8];
      }
#pragma unroll
      for (int nf = 0; nf < 4; ++nf) {
        int row = wc * 64 + nf * 16 + lr;
        bfr[nf] = *(const bf16x8*)&smem[8192 + row * 64 + ((lg + ks * 4) ^ (row & 7)) * 8];
      }
#pragma unroll
      for (int mf = 0; mf < 4; ++mf)
#pragma unroll
        for (int nf = 0; nf < 4; ++nf)
          acc[mf][nf] = __builtin_amdgcn_mfma_f32_16x16x32_bf16(af[mf], bfr[nf], acc[mf][nf], 0, 0, 0);
    }
    __syncthreads();
  }

  if (z < 2) {
    unsigned short* out = z == 0 ? qb : kb;
#pragma unroll
    for (int mf = 0; mf < 4; ++mf)
#pragma unroll
      for (int nf = 0; nf < 4; ++nf) {
        int n = n0 + wc * 64 + nf * 16 + lr;
        int h = n >> 7, d = n & 127;
#pragma unroll
        for (int r = 0; r < 4; ++r) {
          int m = m0 + wr * 64 + mf * 16 + lg * 4 + r;
          int b = m >> 11, s = m & 2047;
          out[(((size_t)(b * NH + h)) * SEQ + s) * HD + d] = f2b(acc[mf][nf][r]);
        }
      }
  } else {
#pragma unroll
    for (int mf = 0; mf < 4; ++mf)
#pragma unroll
      for (int nf = 0; nf < 4; ++nf) {
        int dl = wc * 64 + nf * 16 + lr;
        int sl = wr * 64 + mf * 16 + lg * 4;
        u16x4 pk = {f2b(acc[mf][nf][0]), f2b(acc[mf][nf][1]),
                    f2b(acc[mf][nf][2]), f2b(acc[mf][nf][3])};
        *(u16x4*)&smem[dl * 136 + sl] = pk;
      }
    __syncthreads();
    int b = m0 >> 11, sbase = m0 & 2047;
#pragma unroll
    for (int p = 0; p < 8; ++p) {
      int dl = p * 16 + (tid >> 4);
      int c8 = (tid & 15) * 8;
      u16x8 v = *(const u16x8*)&smem[dl * 136 + c8];
      int n = n0 + dl;
      int h = n >> 7, d = n & 127;
      *(u16x8*)(vtb + (((size_t)(b * NH + h)) * HD + d) * SEQ + sbase + c8) = v;
    }
  }
}

// ---------------- kernel 4: causal flash attention, balanced pairs ----------------
// 512 blocks (16 pair-slots x 32 bh), 4 waves x 16 q-rows per 64-row subtile.
// Each block: subtile qt=x then qt=31-x  ->  exactly 33 KV tiles per block.
__global__ __launch_bounds__(256) void k_attn(
    const unsigned short* __restrict__ qb, const unsigned short* __restrict__ kb,
    const unsigned short* __restrict__ vtb, float* __restrict__ out) {
  __shared__ unsigned short Kl[64 * 128];   // [kv][d], swizzled
  __shared__ unsigned short Vl[128 * 64];   // [d][kv], swizzled
  __shared__ unsigned short Pl[4][16 * 72]; // per-wave [q][kv], pad 72

  // bijective XCD-chunked swizzle: same-bh blocks share an XCD's L2
  const int bid = blockIdx.y * 16 + blockIdx.x;
  const int nid = (bid & 7) * 64 + (bid >> 3);
  const int qx = nid & 15;
  const int bh = nid >> 4;
  const int b = bh >> 4, h = bh & 15;
  const int tid = threadIdx.x;
  const int wave = tid >> 6, lane = tid & 63;
  const int lr = lane & 15, lg = lane >> 4;

  const unsigned short* Qg = qb + (size_t)bh * SEQ * HD;
  const unsigned short* Kg = kb + (size_t)bh * SEQ * HD;
  const unsigned short* Vg = vtb + (size_t)bh * HD * SEQ;
  const float C = 0.12751744155229827f;  // (1/sqrt(128)) * log2(e)

  for (int ph = 0; ph < 2; ++ph) {
    const int qt = ph ? 31 - qx : qx;
    const int q0 = qt * 64;

    bf16x8 qf[4];
#pragma unroll
    for (int ks = 0; ks < 4; ++ks)
      qf[ks] = *(const bf16x8*)&Qg[(size_t)(q0 + wave * 16 + lr) * HD + ks * 32 + lg * 8];

    f32x4 oacc[8] = {};
    float mraw = -1e30f;
    float lsum = 0.f;

    for (int t = 0; t <= qt; ++t) {
      const int kv0 = t * 64;
#pragma unroll
      for (int p = 0; p < 4; ++p) {
        int e = (p * 256 + tid) * 8;
        {
          int row = e >> 7;
          int sc = ((e >> 3) & 15) ^ (row & 7);
          gl_lds16(Kg + (size_t)(kv0 + row) * HD + sc * 8, &Kl[p * 2048 + wave * 512]);
        }
        {
          int row = e >> 6;
          int sc = ((e >> 3) & 7) ^ (row & 7);
          gl_lds16(Vg + (size_t)row * SEQ + kv0 + sc * 8, &Vl[p * 2048 + wave * 512]);
        }
      }
      __syncthreads();

      f32x4 sacc[4] = {};
#pragma unroll
      for (int ks = 0; ks < 4; ++ks) {
        bf16x8 kf[4];
#pragma unroll
        for (int mf = 0; mf < 4; ++mf) {
          int row = mf * 16 + lr;
          kf[mf] = *(const bf16x8*)&Kl[row * 128 + ((lg + ks * 4) ^ (row & 7)) * 8];
        }
#pragma unroll
        for (int mf = 0; mf < 4; ++mf)
          sacc[mf] = __builtin_amdgcn_mfma_f32_16x16x32_bf16(kf[mf], qf[ks], sacc[mf], 0, 0, 0);
      }

      if (t == qt) {  // diagonal tile: causal mask
#pragma unroll
        for (int mf = 0; mf < 4; ++mf)
#pragma unroll
          for (int r = 0; r < 4; ++r) {
            int kv = kv0 + mf * 16 + lg * 4 + r;
            int q = q0 + wave * 16 + lr;
            if (kv > q) sacc[mf][r] = -1e30f;
          }
      }

      // online softmax (column q = lr is lane-local up to a 4-lane reduce)
      float vm = -1e30f;
#pragma unroll
      for (int mf = 0; mf < 4; ++mf)
        vm = fmaxf(vm, fmaxf(fmaxf(sacc[mf][0], sacc[mf][1]),
                             fmaxf(sacc[mf][2], sacc[mf][3])));
      vm = fmaxf(vm, __shfl_xor(vm, 16));
      vm = fmaxf(vm, __shfl_xor(vm, 32));
      float nm = fmaxf(mraw, vm);
      float pfac = exp2f((mraw - nm) * C);
      float mC = nm * C;
      float ssum = 0.f;
#pragma unroll
      for (int mf = 0; mf < 4; ++mf)
#pragma unroll
        for (int r = 0; r < 4; ++r) {
          float pv = exp2f(sacc[mf][r] * C - mC);
          sacc[mf][r] = pv;
          ssum += pv;
        }
      ssum += __shfl_xor(ssum, 16);
      ssum += __shfl_xor(ssum, 32);
      lsum = lsum * pfac + ssum;
      mraw = nm;

      // rescale O by per-row factor
#pragma unroll
      for (int r = 0; r < 4; ++r) {
        float f = __shfl(pfac, lg * 4 + r);
#pragma unroll
        for (int nf8 = 0; nf8 < 8; ++nf8) oacc[nf8][r] *= f;
      }

      // P (bf16) -> per-wave LDS [q][kv]
#pragma unroll
      for (int mf = 0; mf < 4; ++mf) {
        u16x4 pk = {f2b(sacc[mf][0]), f2b(sacc[mf][1]),
                    f2b(sacc[mf][2]), f2b(sacc[mf][3])};
        *(u16x4*)&Pl[wave][lr * 72 + mf * 16 + lg * 4] = pk;
      }
      asm volatile("s_waitcnt lgkmcnt(0)" ::: "memory");

      // O += P . V
#pragma unroll
      for (int ks2 = 0; ks2 < 2; ++ks2) {
        bf16x8 pf = *(const bf16x8*)&Pl[wave][lr * 72 + ks2 * 32 + lg * 8];
#pragma unroll
        for (int nf8 = 0; nf8 < 8; ++nf8) {
          int row = nf8 * 16 + lr;
          bf16x8 vf = *(const bf16x8*)&Vl[row * 64 + ((lg + ks2 * 4) ^ (row & 7)) * 8];
          oacc[nf8] = __builtin_amdgcn_mfma_f32_16x16x32_bf16(pf, vf, oacc[nf8], 0, 0, 0);
        }
      }
      __syncthreads();
    }

    // normalize + store fp32
#pragma unroll
    for (int r = 0; r < 4; ++r) {
      float li = 1.0f / __shfl(lsum, lg * 4 + r);
      int q = q0 + wave * 16 + lg * 4 + r;
      float* orow = out + ((size_t)b * SEQ + q) * DM + h * HD;
#pragma unroll
      for (int nf8 = 0; nf8 < 8; ++nf8)
        orow[nf8 * 16 + lr] = oacc[nf8][r] * li;
    }
  }
}

// ---------------- launcher ----------------
extern "C" void kernel_launch(void* const* d_in, const int* in_sizes, int n_in,
                              void* d_out, int out_size, void* d_ws, size_t ws_size,
                              hipStream_t stream) {
  const float* x  = (const float*)d_in[0];
  const float* Wq = (const float*)d_in[1];
  const float* Wk = (const float*)d_in[2];
  const float* Wv = (const float*)d_in[3];
  float* out = (float*)d_out;
  char* ws = (char*)d_ws;

  unsigned short* xb  = (unsigned short*)(ws);              // 4096x2048 bf16   (16 MB)
  unsigned short* wt  = (unsigned short*)(ws + 16777216);   // 3x 2048x2048 bf16 (24 MB)
  unsigned short* qb  = (unsigned short*)(ws + 41943040);   // [32][2048][128]  (16 MB)
  unsigned short* kb  = (unsigned short*)(ws + 58720256);   // [32][2048][128]  (16 MB)
  unsigned short* vtb = (unsigned short*)(ws + 75497472);   // [32][128][2048]  (16 MB)

  k_cvt_x<<<4096, 256, 0, stream>>>(x, xb);
  dim3 gw(32, 32, 3);
  k_cvt_w<<<gw, 256, 0, stream>>>(Wq, Wk, Wv, wt);
  dim3 gg(32, 16, 3);
  k_qkv<<<gg, 256, 0, stream>>>(xb, wt, qb, kb, vtb);
  dim3 ga(16, 32);
  k_attn<<<ga, 256, 0, stream>>>(qb, kb, vtb, out);
}

// Round 3
// 250.625 us; speedup vs baseline: 1.2242x; 1.0029x over previous
//
#include <hip/hip_runtime.h>

#define DM   2048
#define SEQ  2048
#define NB   2
#define NH   16
#define HD   128

typedef __bf16 bf16x8 __attribute__((ext_vector_type(8)));
typedef float f32x4 __attribute__((ext_vector_type(4)));
typedef unsigned short u16x4 __attribute__((ext_vector_type(4)));
typedef unsigned short u16x8 __attribute__((ext_vector_type(8)));

__device__ __forceinline__ unsigned short f2b(float f) {
  return __builtin_bit_cast(unsigned short, (__bf16)f);
}

__device__ __forceinline__ void gl_lds16(const void* g, void* l) {
  __builtin_amdgcn_global_load_lds(
      (const __attribute__((address_space(1))) void*)g,
      (__attribute__((address_space(3))) void*)l, 16, 0, 0);
}

// ---------------- kernel 1: x fp32 -> bf16 ----------------
__global__ void k_cvt_x(const float* __restrict__ x, unsigned short* __restrict__ xb) {
  int i = blockIdx.x * 256 + threadIdx.x;
  const float4* src = (const float4*)x + (size_t)i * 2;
  float4 a = src[0], c = src[1];
  u16x8 o;
  o[0] = f2b(a.x); o[1] = f2b(a.y); o[2] = f2b(a.z); o[3] = f2b(a.w);
  o[4] = f2b(c.x); o[5] = f2b(c.y); o[6] = f2b(c.z); o[7] = f2b(c.w);
  *((u16x8*)xb + i) = o;
}

// ---------------- kernel 2: W fp32 [K][N] -> bf16 Wt [N][K] ----------------
__global__ void k_cvt_w(const float* __restrict__ Wq, const float* __restrict__ Wk,
                        const float* __restrict__ Wv, unsigned short* __restrict__ wts) {
  const float* W = blockIdx.z == 0 ? Wq : (blockIdx.z == 1 ? Wk : Wv);
  unsigned short* out = wts + (size_t)blockIdx.z * DM * DM;
  __shared__ unsigned short t[64 * 68];  // t[col][row]
  int c0 = blockIdx.x * 64, r0 = blockIdx.y * 64;
  int tr = threadIdx.x >> 4, tc = (threadIdx.x & 15) * 4;
#pragma unroll
  for (int p = 0; p < 4; ++p) {
    int r = p * 16 + tr;
    float4 v = *(const float4*)(W + (size_t)(r0 + r) * DM + c0 + tc);
    t[(tc + 0) * 68 + r] = f2b(v.x);
    t[(tc + 1) * 68 + r] = f2b(v.y);
    t[(tc + 2) * 68 + r] = f2b(v.z);
    t[(tc + 3) * 68 + r] = f2b(v.w);
  }
  __syncthreads();
#pragma unroll
  for (int p = 0; p < 4; ++p) {
    int c = p * 16 + tr;
    u16x4 o = *(const u16x4*)&t[c * 68 + tc];
    *(u16x4*)(out + (size_t)(c0 + c) * DM + r0 + tc) = o;
  }
}

// ---------------- kernel 3: QKV GEMM, 256^2 8-phase (T2+T3+T4+T5) ----------------
// C = x[4096,2048] @ W ; B as Wt[n][k]. 8 waves (2M x 4N), per-wave 128x64.
// LDS: A/B K-tiles double-buffered, 128 KB. Half-tile stream 3-ahead, vmcnt(6).
#define NT_ 32

#define DS_A(QM)                                                              \
  {                                                                           \
    _Pragma("unroll") for (int i_ = 0; i_ < 4; ++i_) {                        \
      int row_ = wr * 128 + (QM)*64 + i_ * 16 + lr;                           \
      _Pragma("unroll") for (int ks_ = 0; ks_ < 2; ++ks_)                     \
        af[i_][ks_] = *(const bf16x8*)&smem[abase + row_ * 64 +               \
                                            (((lg + ks_ * 4) ^ (lr & 7)) * 8)];\
    }                                                                         \
  }

#define DS_B(QN)                                                              \
  {                                                                           \
    _Pragma("unroll") for (int j_ = 0; j_ < 2; ++j_) {                        \
      int row_ = wc * 64 + ((QN)*2 + j_) * 16 + lr;                           \
      _Pragma("unroll") for (int ks_ = 0; ks_ < 2; ++ks_)                     \
        bf[(QN)*2 + j_][ks_] =                                                \
            *(const bf16x8*)&smem[bbase + row_ * 64 +                         \
                                  (((lg + ks_ * 4) ^ (lr & 7)) * 8)];         \
    }                                                                         \
  }

#define MFMA_Q(QM, QN)                                                        \
  {                                                                           \
    _Pragma("unroll") for (int i_ = 0; i_ < 4; ++i_)                          \
    _Pragma("unroll") for (int j_ = 0; j_ < 2; ++j_)                          \
    _Pragma("unroll") for (int ks_ = 0; ks_ < 2; ++ks_)                       \
      acc[(QM)*4 + i_][(QN)*2 + j_] = __builtin_amdgcn_mfma_f32_16x16x32_bf16(\
          af[i_][ks_], bf[(QN)*2 + j_][ks_], acc[(QM)*4 + i_][(QN)*2 + j_],   \
          0, 0, 0);                                                           \
  }

// region R: 0=A rows{0-63,128-191} 1=B rows{0-127} 2=B rows{128-255} 3=A rows{64-127,192-255}
#define STAGE(R, H)                                                           \
  do {                                                                        \
    const int h_ = (H);                                                       \
    if (h_ < 4 * NT_) {                                                       \
      const int ktS_ = h_ >> 2;                                               \
      const unsigned lb_ = ((R) == 0 || (R) == 3) ? ((ktS_ & 1) * 16384u)     \
                               : (32768u + (ktS_ & 1) * 16384u);              \
      const unsigned short* sM_ = ((R) == 0 || (R) == 3) ? Ag : Bg;           \
      const int rb0_ = ((R) == 0) ? 0 : ((R) == 1) ? 0 : ((R) == 2) ? 128 : 64;\
      const int rb1_ = ((R) == 0) ? 128 : ((R) == 1) ? 64 : ((R) == 2) ? 192 : 192;\
      gl_lds16(sM_ + (size_t)(rb0_ + srow) * DM + ktS_ * 64 + sgcol,          \
               &smem[lb_ + rb0_ * 64 + wave * 512]);                          \
      gl_lds16(sM_ + (size_t)(rb1_ + srow) * DM + ktS_ * 64 + sgcol,          \
               &smem[lb_ + rb1_ * 64 + wave * 512]);                          \
    }                                                                         \
  } while (0)

__global__ __launch_bounds__(512, 2) void k_qkv(
    const unsigned short* __restrict__ xb, const unsigned short* __restrict__ wts,
    unsigned short* __restrict__ qb, unsigned short* __restrict__ kb,
    unsigned short* __restrict__ vtb) {
  __shared__ unsigned short smem[65536];  // A:[0,32768) B:[32768,65536), dbuf

  // bijective XCD swizzle over 384 blocks
  const int id = blockIdx.x;
  const int swz = (id & 7) * 48 + (id >> 3);
  const int z = swz >> 7;
  const int rem = swz & 127;
  const int m0 = (rem >> 3) * 256;
  const int n0 = (rem & 7) * 256;

  const unsigned short* Ag = xb + (size_t)m0 * DM;
  const unsigned short* Bg = wts + (size_t)z * DM * DM + (size_t)n0 * DM;

  const int tid = threadIdx.x;
  const int wave = tid >> 6, lane = tid & 63;
  const int lr = lane & 15, lg = lane >> 4;
  const int wr = wave >> 2, wc = wave & 3;
  const int srow = tid >> 3;
  const int sgcol = ((tid & 7) ^ (srow & 7)) * 8;

  f32x4 acc[8][4] = {};
  bf16x8 af[4][2], bf[4][2];

  // prologue: tile0 all 4 halves, then tile1 first 3 halves
  STAGE(0, 0); STAGE(1, 1); STAGE(2, 2); STAGE(3, 3);
  asm volatile("s_waitcnt vmcnt(4)" ::: "memory");
  STAGE(0, 4); STAGE(1, 5); STAGE(2, 6);
  asm volatile("s_waitcnt vmcnt(6)" ::: "memory");
  __builtin_amdgcn_s_barrier();

  for (int t = 0; t < NT_; ++t) {
    const unsigned abase = (t & 1) * 16384u;
    const unsigned bbase = 32768u + (t & 1) * 16384u;

    // phase 0: quadrant (0,0); 12 ds_reads; stage (t+1).H3
    DS_A(0); DS_B(0);
    STAGE(3, 4 * t + 7);
    asm volatile("s_waitcnt lgkmcnt(8)" ::: "memory");
    __builtin_amdgcn_s_barrier();
    asm volatile("s_waitcnt lgkmcnt(0)" ::: "memory");
    __builtin_amdgcn_sched_barrier(0);
    __builtin_amdgcn_s_setprio(1);
    MFMA_Q(0, 0);
    __builtin_amdgcn_s_setprio(0);
    __builtin_amdgcn_s_barrier();

    // phase 1: quadrant (0,1); stage (t+2).H0
    DS_B(1);
    STAGE(0, 4 * t + 8);
    __builtin_amdgcn_s_barrier();
    asm volatile("s_waitcnt lgkmcnt(0)" ::: "memory");
    __builtin_amdgcn_sched_barrier(0);
    __builtin_amdgcn_s_setprio(1);
    MFMA_Q(0, 1);
    __builtin_amdgcn_s_setprio(0);
    __builtin_amdgcn_s_barrier();

    // phase 2: quadrant (1,0); stage (t+2).H1
    DS_A(1);
    STAGE(1, 4 * t + 9);
    __builtin_amdgcn_s_barrier();
    asm volatile("s_waitcnt lgkmcnt(0)" ::: "memory");
    __builtin_amdgcn_sched_barrier(0);
    __builtin_amdgcn_s_setprio(1);
    MFMA_Q(1, 0);
    __builtin_amdgcn_s_setprio(0);
    __builtin_amdgcn_s_barrier();

    // phase 3: quadrant (1,1); stage (t+2).H2; counted vmcnt gates tile t+1
    STAGE(2, 4 * t + 10);
    if (t < NT_ - 2)
      asm volatile("s_waitcnt vmcnt(6)" ::: "memory");
    else
      asm volatile("s_waitcnt vmcnt(0)" ::: "memory");
    __builtin_amdgcn_s_barrier();
    __builtin_amdgcn_s_setprio(1);
    MFMA_Q(1, 1);
    __builtin_amdgcn_s_setprio(0);
    __builtin_amdgcn_s_barrier();
  }

  if (z < 2) {
    unsigned short* out = z == 0 ? qb : kb;
#pragma unroll
    for (int mf = 0; mf < 8; ++mf)
#pragma unroll
      for (int nf = 0; nf < 4; ++nf) {
        int n = n0 + wc * 64 + nf * 16 + lr;
        int h = n >> 7, d = n & 127;
#pragma unroll
        for (int r = 0; r < 4; ++r) {
          int m = m0 + wr * 128 + mf * 16 + lg * 4 + r;
          int b = m >> 11, s = m & 2047;
          out[(((size_t)(b * NH + h)) * SEQ + s) * HD + d] = f2b(acc[mf][nf][r]);
        }
      }
  } else {
    // transpose 256x256 C tile through smem (granule-XOR swizzled), write V^T [bh][d][s]
#pragma unroll
    for (int mf = 0; mf < 8; ++mf)
#pragma unroll
      for (int nf = 0; nf < 4; ++nf) {
        int dl = wc * 64 + nf * 16 + lr;
        int gi = wr * 32 + mf * 4 + lg;         // sl/4
        int gs = gi ^ ((dl & 7) << 3);
        u16x4 pk = {f2b(acc[mf][nf][0]), f2b(acc[mf][nf][1]),
                    f2b(acc[mf][nf][2]), f2b(acc[mf][nf][3])};
        *(u16x4*)&smem[dl * 256 + gs * 4] = pk;
      }
    __builtin_amdgcn_s_barrier();
    asm volatile("s_waitcnt lgkmcnt(0)" ::: "memory");
    int b = m0 >> 11, sbase = m0 & 2047;
#pragma unroll
    for (int p = 0; p < 16; ++p) {
      int f = p * 512 + tid;
      int dl = f >> 5, c8 = f & 31;
      int g0 = (c8 * 2) ^ ((dl & 7) << 3);
      u16x8 v = *(const u16x8*)&smem[dl * 256 + g0 * 4];
      int n = n0 + dl;
      int h = n >> 7, d = n & 127;
      *(u16x8*)(vtb + (((size_t)(b * NH + h)) * HD + d) * SEQ + sbase + c8 * 8) = v;
    }
  }
}

// ---------------- kernel 4: causal flash attention, balanced pairs ----------------
__global__ __launch_bounds__(256) void k_attn(
    const unsigned short* __restrict__ qb, const unsigned short* __restrict__ kb,
    const unsigned short* __restrict__ vtb, float* __restrict__ out) {
  __shared__ unsigned short Kl[64 * 128];   // [kv][d], swizzled
  __shared__ unsigned short Vl[128 * 64];   // [d][kv], swizzled
  __shared__ unsigned short Pl[4][16 * 72]; // per-wave [q][kv], pad 72

  const int bid = blockIdx.y * 16 + blockIdx.x;
  const int nid = (bid & 7) * 64 + (bid >> 3);
  const int qx = nid & 15;
  const int bh = nid >> 4;
  const int b = bh >> 4, h = bh & 15;
  const int tid = threadIdx.x;
  const int wave = tid >> 6, lane = tid & 63;
  const int lr = lane & 15, lg = lane >> 4;

  const unsigned short* Qg = qb + (size_t)bh * SEQ * HD;
  const unsigned short* Kg = kb + (size_t)bh * SEQ * HD;
  const unsigned short* Vg = vtb + (size_t)bh * HD * SEQ;
  const float C = 0.12751744155229827f;  // (1/sqrt(128)) * log2(e)

  for (int ph = 0; ph < 2; ++ph) {
    const int qt = ph ? 31 - qx : qx;
    const int q0 = qt * 64;

    bf16x8 qf[4];
#pragma unroll
    for (int ks = 0; ks < 4; ++ks)
      qf[ks] = *(const bf16x8*)&Qg[(size_t)(q0 + wave * 16 + lr) * HD + ks * 32 + lg * 8];

    f32x4 oacc[8] = {};
    float mraw = -1e30f;
    float lsum = 0.f;

    for (int t = 0; t <= qt; ++t) {
      const int kv0 = t * 64;
#pragma unroll
      for (int p = 0; p < 4; ++p) {
        int e = (p * 256 + tid) * 8;
        {
          int row = e >> 7;
          int sc = ((e >> 3) & 15) ^ (row & 7);
          gl_lds16(Kg + (size_t)(kv0 + row) * HD + sc * 8, &Kl[p * 2048 + wave * 512]);
        }
        {
          int row = e >> 6;
          int sc = ((e >> 3) & 7) ^ (row & 7);
          gl_lds16(Vg + (size_t)row * SEQ + kv0 + sc * 8, &Vl[p * 2048 + wave * 512]);
        }
      }
      __syncthreads();

      f32x4 sacc[4] = {};
#pragma unroll
      for (int ks = 0; ks < 4; ++ks) {
        bf16x8 kf[4];
#pragma unroll
        for (int mf = 0; mf < 4; ++mf) {
          int row = mf * 16 + lr;
          kf[mf] = *(const bf16x8*)&Kl[row * 128 + ((lg + ks * 4) ^ (row & 7)) * 8];
        }
#pragma unroll
        for (int mf = 0; mf < 4; ++mf)
          sacc[mf] = __builtin_amdgcn_mfma_f32_16x16x32_bf16(kf[mf], qf[ks], sacc[mf], 0, 0, 0);
      }

      if (t == qt) {
#pragma unroll
        for (int mf = 0; mf < 4; ++mf)
#pragma unroll
          for (int r = 0; r < 4; ++r) {
            int kv = kv0 + mf * 16 + lg * 4 + r;
            int q = q0 + wave * 16 + lr;
            if (kv > q) sacc[mf][r] = -1e30f;
          }
      }

      float vm = -1e30f;
#pragma unroll
      for (int mf = 0; mf < 4; ++mf)
        vm = fmaxf(vm, fmaxf(fmaxf(sacc[mf][0], sacc[mf][1]),
                             fmaxf(sacc[mf][2], sacc[mf][3])));
      vm = fmaxf(vm, __shfl_xor(vm, 16));
      vm = fmaxf(vm, __shfl_xor(vm, 32));
      float nm = fmaxf(mraw, vm);
      float pfac = exp2f((mraw - nm) * C);
      float mC = nm * C;
      float ssum = 0.f;
#pragma unroll
      for (int mf = 0; mf < 4; ++mf)
#pragma unroll
        for (int r = 0; r < 4; ++r) {
          float pv = exp2f(sacc[mf][r] * C - mC);
          sacc[mf][r] = pv;
          ssum += pv;
        }
      ssum += __shfl_xor(ssum, 16);
      ssum += __shfl_xor(ssum, 32);
      lsum = lsum * pfac + ssum;
      mraw = nm;

#pragma unroll
      for (int r = 0; r < 4; ++r) {
        float f = __shfl(pfac, lg * 4 + r);
#pragma unroll
        for (int nf8 = 0; nf8 < 8; ++nf8) oacc[nf8][r] *= f;
      }

#pragma unroll
      for (int mf = 0; mf < 4; ++mf) {
        u16x4 pk = {f2b(sacc[mf][0]), f2b(sacc[mf][1]),
                    f2b(sacc[mf][2]), f2b(sacc[mf][3])};
        *(u16x4*)&Pl[wave][lr * 72 + mf * 16 + lg * 4] = pk;
      }
      asm volatile("s_waitcnt lgkmcnt(0)" ::: "memory");

#pragma unroll
      for (int ks2 = 0; ks2 < 2; ++ks2) {
        bf16x8 pf = *(const bf16x8*)&Pl[wave][lr * 72 + ks2 * 32 + lg * 8];
#pragma unroll
        for (int nf8 = 0; nf8 < 8; ++nf8) {
          int row = nf8 * 16 + lr;
          bf16x8 vf = *(const bf16x8*)&Vl[row * 64 + ((lg + ks2 * 4) ^ (row & 7)) * 8];
          oacc[nf8] = __builtin_amdgcn_mfma_f32_16x16x32_bf16(pf, vf, oacc[nf8], 0, 0, 0);
        }
      }
      __syncthreads();
    }

#pragma unroll
    for (int r = 0; r < 4; ++r) {
      float li = 1.0f / __shfl(lsum, lg * 4 + r);
      int q = q0 + wave * 16 + lg * 4 + r;
      float* orow = out + ((size_t)b * SEQ + q) * DM + h * HD;
#pragma unroll
      for (int nf8 = 0; nf8 < 8; ++nf8)
        orow[nf8 * 16 + lr] = oacc[nf8][r] * li;
    }
  }
}

// ---------------- launcher ----------------
extern "C" void kernel_launch(void* const* d_in, const int* in_sizes, int n_in,
                              void* d_out, int out_size, void* d_ws, size_t ws_size,
                              hipStream_t stream) {
  const float* x  = (const float*)d_in[0];
  const float* Wq = (const float*)d_in[1];
  const float* Wk = (const float*)d_in[2];
  const float* Wv = (const float*)d_in[3];
  float* out = (float*)d_out;
  char* ws = (char*)d_ws;

  unsigned short* xb  = (unsigned short*)(ws);              // 4096x2048 bf16   (16 MB)
  unsigned short* wt  = (unsigned short*)(ws + 16777216);   // 3x 2048x2048 bf16 (24 MB)
  unsigned short* qb  = (unsigned short*)(ws + 41943040);   // [32][2048][128]  (16 MB)
  unsigned short* kb  = (unsigned short*)(ws + 58720256);   // [32][2048][128]  (16 MB)
  unsigned short* vtb = (unsigned short*)(ws + 75497472);   // [32][128][2048]  (16 MB)

  k_cvt_x<<<4096, 256, 0, stream>>>(x, xb);
  dim3 gw(32, 32, 3);
  k_cvt_w<<<gw, 256, 0, stream>>>(Wq, Wk, Wv, wt);
  k_qkv<<<384, 512, 0, stream>>>(xb, wt, qb, kb, vtb);
  dim3 ga(16, 32);
  k_attn<<<ga, 256, 0, stream>>>(qb, kb, vtb, out);
}

// Round 4
// 233.967 us; speedup vs baseline: 1.3114x; 1.0712x over previous
//
#include <hip/hip_runtime.h>

#define DM   2048
#define SEQ  2048
#define NB   2
#define NH   16
#define HD   128

typedef __bf16 bf16x8 __attribute__((ext_vector_type(8)));
typedef float f32x4 __attribute__((ext_vector_type(4)));
typedef unsigned short u16x4 __attribute__((ext_vector_type(4)));
typedef unsigned short u16x8 __attribute__((ext_vector_type(8)));

__device__ __forceinline__ unsigned short f2b(float f) {
  return __builtin_bit_cast(unsigned short, (__bf16)f);
}

__device__ __forceinline__ void gl_lds16(const void* g, void* l) {
  __builtin_amdgcn_global_load_lds(
      (const __attribute__((address_space(1))) void*)g,
      (__attribute__((address_space(3))) void*)l, 16, 0, 0);
}

// ---------------- kernel 1: x fp32 -> bf16 ----------------
__global__ void k_cvt_x(const float* __restrict__ x, unsigned short* __restrict__ xb) {
  int i = blockIdx.x * 256 + threadIdx.x;
  const float4* src = (const float4*)x + (size_t)i * 2;
  float4 a = src[0], c = src[1];
  u16x8 o;
  o[0] = f2b(a.x); o[1] = f2b(a.y); o[2] = f2b(a.z); o[3] = f2b(a.w);
  o[4] = f2b(c.x); o[5] = f2b(c.y); o[6] = f2b(c.z); o[7] = f2b(c.w);
  *((u16x8*)xb + i) = o;
}

// ---------------- kernel 2: W fp32 [K][N] -> bf16 Wt [N][K] ----------------
__global__ void k_cvt_w(const float* __restrict__ Wq, const float* __restrict__ Wk,
                        const float* __restrict__ Wv, unsigned short* __restrict__ wts) {
  const float* W = blockIdx.z == 0 ? Wq : (blockIdx.z == 1 ? Wk : Wv);
  unsigned short* out = wts + (size_t)blockIdx.z * DM * DM;
  __shared__ unsigned short t[64 * 68];  // t[col][row]
  int c0 = blockIdx.x * 64, r0 = blockIdx.y * 64;
  int tr = threadIdx.x >> 4, tc = (threadIdx.x & 15) * 4;
#pragma unroll
  for (int p = 0; p < 4; ++p) {
    int r = p * 16 + tr;
    float4 v = *(const float4*)(W + (size_t)(r0 + r) * DM + c0 + tc);
    t[(tc + 0) * 68 + r] = f2b(v.x);
    t[(tc + 1) * 68 + r] = f2b(v.y);
    t[(tc + 2) * 68 + r] = f2b(v.z);
    t[(tc + 3) * 68 + r] = f2b(v.w);
  }
  __syncthreads();
#pragma unroll
  for (int p = 0; p < 4; ++p) {
    int c = p * 16 + tr;
    u16x4 o = *(const u16x4*)&t[c * 68 + tc];
    *(u16x4*)(out + (size_t)(c0 + c) * DM + r0 + tc) = o;
  }
}

// ---------------- kernel 3: QKV GEMM, 128x256 tile, 2-phase 8-wave ----------------
// grid 768 = 32m x 8n x 3z = exactly 3 blocks/CU. LDS 96KB dbuf.
// Waves: wr = wave>>2 (2 M-halves of 64), wc = wave&3 (4 N-quarters of 64).
// B region split by phase-read rows: U1' = stripes {0-31,64-95,128-159,192-223} (P0),
// U2' = {32-63,96-127,160-191,224-255} (P1). Stage: U2'(t+1) in P0; A(t+2),U1'(t+2) in P1.
#define NT_ 32

#define ST_A(T)                                                                \
  if ((T) < NT_) {                                                             \
    const int ktS = (T);                                                       \
    const unsigned ab_ = (ktS & 1) * 8192u;                                    \
    gl_lds16(Ag + (size_t)srow * DM + ktS * 64 + sgcol, &smem[ab_ + bo0]);     \
    gl_lds16(Ag + (size_t)(64 + srow) * DM + ktS * 64 + sgcol,                 \
             &smem[ab_ + 4096 + bo0]);                                         \
  }

#define ST_B1(T)                                                               \
  if ((T) < NT_) {                                                             \
    const int ktS = (T);                                                       \
    const unsigned bb_ = 16384u + (ktS & 1) * 16384u;                          \
    gl_lds16(Bg + (size_t)grB * DM + ktS * 64 + sgcol, &smem[bb_ + bo1]);      \
    gl_lds16(Bg + (size_t)(grB + 128) * DM + ktS * 64 + sgcol,                 \
             &smem[bb_ + 8192 + bo1]);                                         \
  }

#define ST_B2(T)                                                               \
  if ((T) < NT_) {                                                             \
    const int ktS = (T);                                                       \
    const unsigned bb_ = 16384u + (ktS & 1) * 16384u;                          \
    gl_lds16(Bg + (size_t)(grB + 32) * DM + ktS * 64 + sgcol,                  \
             &smem[bb_ + 2048 + bo1]);                                         \
    gl_lds16(Bg + (size_t)(grB + 160) * DM + ktS * 64 + sgcol,                 \
             &smem[bb_ + 10240 + bo1]);                                        \
  }

#define DS_A_ALL                                                               \
  {                                                                            \
    _Pragma("unroll") for (int mf_ = 0; mf_ < 4; ++mf_) {                      \
      int row_ = wr * 64 + mf_ * 16 + lr;                                      \
      _Pragma("unroll") for (int ks_ = 0; ks_ < 2; ++ks_)                      \
        af[mf_][ks_] = *(const bf16x8*)&smem[ab + row_ * 64 +                  \
                                             (((lg + ks_ * 4) ^ (lr & 7)) * 8)];\
    }                                                                          \
  }

#define DS_B(NF, J)                                                            \
  {                                                                            \
    int row_ = wc * 64 + (NF)*16 + lr;                                         \
    _Pragma("unroll") for (int ks_ = 0; ks_ < 2; ++ks_)                        \
      bfr[J][ks_] = *(const bf16x8*)&smem[bb + row_ * 64 +                     \
                                          (((lg + ks_ * 4) ^ (lr & 7)) * 8)];  \
  }

#define MFMA_P(NFB)                                                            \
  {                                                                            \
    _Pragma("unroll") for (int mf_ = 0; mf_ < 4; ++mf_)                        \
    _Pragma("unroll") for (int j_ = 0; j_ < 2; ++j_)                           \
    _Pragma("unroll") for (int ks_ = 0; ks_ < 2; ++ks_)                        \
      acc[mf_][(NFB) + j_] = __builtin_amdgcn_mfma_f32_16x16x32_bf16(          \
          af[mf_][ks_], bfr[j_][ks_], acc[mf_][(NFB) + j_], 0, 0, 0);          \
  }

__global__ __launch_bounds__(512, 2) void k_qkv(
    const unsigned short* __restrict__ xb, const unsigned short* __restrict__ wts,
    unsigned short* __restrict__ qb, unsigned short* __restrict__ kb,
    unsigned short* __restrict__ vtb) {
  __shared__ unsigned short smem[49152];  // A dbuf [0,16384) B dbuf [16384,49152)

  // bijective XCD swizzle over 768 blocks
  const int id = blockIdx.x;
  const int swz = (id & 7) * 96 + (id >> 3);
  const int z = swz >> 8;
  const int rem = swz & 255;
  const int m0 = (rem >> 3) * 128;
  const int n0 = (rem & 7) * 256;

  const unsigned short* Ag = xb + (size_t)m0 * DM;
  const unsigned short* Bg = wts + (size_t)z * DM * DM + (size_t)n0 * DM;

  const int tid = threadIdx.x;
  const int wave = tid >> 6, lane = tid & 63;
  const int lr = lane & 15, lg = lane >> 4;
  const int wr = wave >> 2, wc = wave & 3;
  const int srow = tid >> 3;
  const int sgcol = ((tid & 7) ^ (srow & 7)) * 8;
  const int grB = srow + (srow & 32);
  const unsigned bo0 = wave * 512u;
  const unsigned bo1 = wave * 512u + ((wave & 4) << 9);

  f32x4 acc[4][4] = {};
  bf16x8 af[4][2], bfr[2][2];

  // prologue: tile0 complete + tile1 {A, U1'}
  ST_A(0); ST_B1(0); ST_B2(0); ST_A(1); ST_B1(1);
  asm volatile("s_waitcnt vmcnt(4)" ::: "memory");
  __builtin_amdgcn_s_barrier();

  for (int t = 0; t < NT_; ++t) {
    const unsigned ab = (t & 1) * 8192u;
    const unsigned bb = 16384u + (t & 1) * 16384u;

    // ---- P0: A-frags + B-lo; stage U2'(t+1) ----
    DS_A_ALL;
    DS_B(0, 0); DS_B(1, 1);
    ST_B2(t + 1);
    asm volatile("s_waitcnt lgkmcnt(8)" ::: "memory");
    __builtin_amdgcn_s_barrier();
    asm volatile("s_waitcnt lgkmcnt(0)" ::: "memory");
    __builtin_amdgcn_sched_barrier(0);
    __builtin_amdgcn_s_setprio(1);
    MFMA_P(0);
    __builtin_amdgcn_s_setprio(0);
    __builtin_amdgcn_s_barrier();

    // ---- P1: B-hi; stage A(t+2), U1'(t+2); counted vmcnt gates tile t+1 ----
    DS_B(2, 0); DS_B(3, 1);
    ST_A(t + 2); ST_B1(t + 2);
    if (t < NT_ - 2)
      asm volatile("s_waitcnt vmcnt(4)" ::: "memory");
    else
      asm volatile("s_waitcnt vmcnt(0)" ::: "memory");
    __builtin_amdgcn_s_barrier();
    asm volatile("s_waitcnt lgkmcnt(0)" ::: "memory");
    __builtin_amdgcn_sched_barrier(0);
    __builtin_amdgcn_s_setprio(1);
    MFMA_P(2);
    __builtin_amdgcn_s_setprio(0);
    __builtin_amdgcn_s_barrier();
  }

  if (z < 2) {
    unsigned short* out = z == 0 ? qb : kb;
#pragma unroll
    for (int mf = 0; mf < 4; ++mf)
#pragma unroll
      for (int nf = 0; nf < 4; ++nf) {
        int n = n0 + wc * 64 + nf * 16 + lr;
        int h = n >> 7, d = n & 127;
#pragma unroll
        for (int r = 0; r < 4; ++r) {
          int m = m0 + wr * 64 + mf * 16 + lg * 4 + r;
          int b = m >> 11, s = m & 2047;
          out[(((size_t)(b * NH + h)) * SEQ + s) * HD + d] = f2b(acc[mf][nf][r]);
        }
      }
  } else {
    // transpose 128x256 C tile through smem (granule-XOR), write V^T [bh][d][s]
#pragma unroll
    for (int mf = 0; mf < 4; ++mf)
#pragma unroll
      for (int nf = 0; nf < 4; ++nf) {
        int dl = wc * 64 + nf * 16 + lr;              // 0..255 (d-dir)
        int g = wr * 16 + mf * 4 + lg;                // sl/4, 0..31
        int gs = g ^ ((dl & 7) << 2);
        u16x4 pk = {f2b(acc[mf][nf][0]), f2b(acc[mf][nf][1]),
                    f2b(acc[mf][nf][2]), f2b(acc[mf][nf][3])};
        *(u16x4*)&smem[dl * 128 + gs * 4] = pk;
      }
    __builtin_amdgcn_s_barrier();
    asm volatile("s_waitcnt lgkmcnt(0)" ::: "memory");
    int b = m0 >> 11, sbase = m0 & 2047;
#pragma unroll
    for (int p = 0; p < 8; ++p) {
      int f = p * 512 + tid;
      int dl = f >> 4, c8 = f & 15;
      int g0 = (2 * c8) ^ ((dl & 7) << 2);
      u16x8 v = *(const u16x8*)&smem[dl * 128 + g0 * 4];
      int n = n0 + dl;
      int h = n >> 7, d = n & 127;
      *(u16x8*)(vtb + (((size_t)(b * NH + h)) * HD + d) * SEQ + sbase + c8 * 8) = v;
    }
  }
}

// ---------------- kernel 4: causal flash attention, balanced + K/V dbuf (T14) ----------------
__global__ __launch_bounds__(256) void k_attn(
    const unsigned short* __restrict__ qb, const unsigned short* __restrict__ kb,
    const unsigned short* __restrict__ vtb, float* __restrict__ out) {
  __shared__ unsigned short Kl[2][64 * 128];   // [kv][d], swizzled
  __shared__ unsigned short Vl[2][128 * 64];   // [d][kv], swizzled
  __shared__ unsigned short Pl[4][16 * 72];    // per-wave [q][kv], pad 72

  const int bid = blockIdx.y * 16 + blockIdx.x;
  const int nid = (bid & 7) * 64 + (bid >> 3);
  const int qx = nid & 15;
  const int bh = nid >> 4;
  const int b = bh >> 4, h = bh & 15;
  const int tid = threadIdx.x;
  const int wave = tid >> 6, lane = tid & 63;
  const int lr = lane & 15, lg = lane >> 4;

  const unsigned short* Qg = qb + (size_t)bh * SEQ * HD;
  const unsigned short* Kg = kb + (size_t)bh * SEQ * HD;
  const unsigned short* Vg = vtb + (size_t)bh * HD * SEQ;
  const float C = 0.12751744155229827f;  // (1/sqrt(128)) * log2(e)

#define STAGE_KV(T, BUF)                                                       \
  {                                                                            \
    const int kv0_ = (T)*64;                                                   \
    _Pragma("unroll") for (int p = 0; p < 4; ++p) {                            \
      int e = (p * 256 + tid) * 8;                                             \
      {                                                                        \
        int row = e >> 7;                                                      \
        int sc = ((e >> 3) & 15) ^ (row & 7);                                  \
        gl_lds16(Kg + (size_t)(kv0_ + row) * HD + sc * 8,                      \
                 &Kl[BUF][p * 2048 + wave * 512]);                             \
      }                                                                        \
      {                                                                        \
        int row = e >> 6;                                                      \
        int sc = ((e >> 3) & 7) ^ (row & 7);                                   \
        gl_lds16(Vg + (size_t)row * SEQ + kv0_ + sc * 8,                       \
                 &Vl[BUF][p * 2048 + wave * 512]);                             \
      }                                                                        \
    }                                                                          \
  }

  for (int ph = 0; ph < 2; ++ph) {
    const int qt = ph ? 31 - qx : qx;
    const int q0 = qt * 64;

    bf16x8 qf[4];
#pragma unroll
    for (int ks = 0; ks < 4; ++ks)
      qf[ks] = *(const bf16x8*)&Qg[(size_t)(q0 + wave * 16 + lr) * HD + ks * 32 + lg * 8];

    f32x4 oacc[8] = {};
    float mraw = -1e30f;
    float lsum = 0.f;

    STAGE_KV(0, 0);
    asm volatile("s_waitcnt vmcnt(0)" ::: "memory");
    __syncthreads();

    for (int t = 0; t <= qt; ++t) {
      const int cur = t & 1;
      if (t < qt) STAGE_KV(t + 1, cur ^ 1);

      f32x4 sacc[4] = {};
#pragma unroll
      for (int ks = 0; ks < 4; ++ks) {
        bf16x8 kf[4];
#pragma unroll
        for (int mf = 0; mf < 4; ++mf) {
          int row = mf * 16 + lr;
          kf[mf] = *(const bf16x8*)&Kl[cur][row * 128 + ((lg + ks * 4) ^ (row & 7)) * 8];
        }
#pragma unroll
        for (int mf = 0; mf < 4; ++mf)
          sacc[mf] = __builtin_amdgcn_mfma_f32_16x16x32_bf16(kf[mf], qf[ks], sacc[mf], 0, 0, 0);
      }

      if (t == qt) {  // diagonal tile: causal mask
        const int kv0 = t * 64;
#pragma unroll
        for (int mf = 0; mf < 4; ++mf)
#pragma unroll
          for (int r = 0; r < 4; ++r) {
            int kv = kv0 + mf * 16 + lg * 4 + r;
            int q = q0 + wave * 16 + lr;
            if (kv > q) sacc[mf][r] = -1e30f;
          }
      }

      // online softmax (row q = lr, lane-local up to 4-lane reduce)
      float vm = -1e30f;
#pragma unroll
      for (int mf = 0; mf < 4; ++mf)
        vm = fmaxf(vm, fmaxf(fmaxf(sacc[mf][0], sacc[mf][1]),
                             fmaxf(sacc[mf][2], sacc[mf][3])));
      vm = fmaxf(vm, __shfl_xor(vm, 16));
      vm = fmaxf(vm, __shfl_xor(vm, 32));
      float nm = fmaxf(mraw, vm);
      float pfac = exp2f((mraw - nm) * C);
      float mC = nm * C;
      float ssum = 0.f;
#pragma unroll
      for (int mf = 0; mf < 4; ++mf)
#pragma unroll
        for (int r = 0; r < 4; ++r) {
          float pv = exp2f(sacc[mf][r] * C - mC);
          sacc[mf][r] = pv;
          ssum += pv;
        }
      ssum += __shfl_xor(ssum, 16);
      ssum += __shfl_xor(ssum, 32);
      lsum = lsum * pfac + ssum;
      mraw = nm;

#pragma unroll
      for (int r = 0; r < 4; ++r) {
        float f = __shfl(pfac, lg * 4 + r);
#pragma unroll
        for (int nf8 = 0; nf8 < 8; ++nf8) oacc[nf8][r] *= f;
      }

#pragma unroll
      for (int mf = 0; mf < 4; ++mf) {
        u16x4 pk = {f2b(sacc[mf][0]), f2b(sacc[mf][1]),
                    f2b(sacc[mf][2]), f2b(sacc[mf][3])};
        *(u16x4*)&Pl[wave][lr * 72 + mf * 16 + lg * 4] = pk;
      }
      asm volatile("s_waitcnt lgkmcnt(0)" ::: "memory");

#pragma unroll
      for (int ks2 = 0; ks2 < 2; ++ks2) {
        bf16x8 pf = *(const bf16x8*)&Pl[wave][lr * 72 + ks2 * 32 + lg * 8];
#pragma unroll
        for (int nf8 = 0; nf8 < 8; ++nf8) {
          int row = nf8 * 16 + lr;
          bf16x8 vf = *(const bf16x8*)&Vl[cur][row * 64 + ((lg + ks2 * 4) ^ (row & 7)) * 8];
          oacc[nf8] = __builtin_amdgcn_mfma_f32_16x16x32_bf16(pf, vf, oacc[nf8], 0, 0, 0);
        }
      }
      asm volatile("s_waitcnt vmcnt(0)" ::: "memory");  // next tile staged (hidden under compute)
      __syncthreads();
    }

    // normalize + store fp32
#pragma unroll
    for (int r = 0; r < 4; ++r) {
      float li = 1.0f / __shfl(lsum, lg * 4 + r);
      int q = q0 + wave * 16 + lg * 4 + r;
      float* orow = out + ((size_t)b * SEQ + q) * DM + h * HD;
#pragma unroll
      for (int nf8 = 0; nf8 < 8; ++nf8)
        orow[nf8 * 16 + lr] = oacc[nf8][r] * li;
    }
  }
}

// ---------------- launcher ----------------
extern "C" void kernel_launch(void* const* d_in, const int* in_sizes, int n_in,
                              void* d_out, int out_size, void* d_ws, size_t ws_size,
                              hipStream_t stream) {
  const float* x  = (const float*)d_in[0];
  const float* Wq = (const float*)d_in[1];
  const float* Wk = (const float*)d_in[2];
  const float* Wv = (const float*)d_in[3];
  float* out = (float*)d_out;
  char* ws = (char*)d_ws;

  unsigned short* xb  = (unsigned short*)(ws);              // 4096x2048 bf16   (16 MB)
  unsigned short* wt  = (unsigned short*)(ws + 16777216);   // 3x 2048x2048 bf16 (24 MB)
  unsigned short* qb  = (unsigned short*)(ws + 41943040);   // [32][2048][128]  (16 MB)
  unsigned short* kb  = (unsigned short*)(ws + 58720256);   // [32][2048][128]  (16 MB)
  unsigned short* vtb = (unsigned short*)(ws + 75497472);   // [32][128][2048]  (16 MB)

  k_cvt_x<<<4096, 256, 0, stream>>>(x, xb);
  dim3 gw(32, 32, 3);
  k_cvt_w<<<gw, 256, 0, stream>>>(Wq, Wk, Wv, wt);
  k_qkv<<<768, 512, 0, stream>>>(xb, wt, qb, kb, vtb);
  dim3 ga(16, 32);
  k_attn<<<ga, 256, 0, stream>>>(qb, kb, vtb, out);
}